// Round 9
// baseline (1066.817 us; speedup 1.0000x reference)
//
#include <hip/hip_runtime.h>
#include <utility>

// Problem constants: DIM_IN=128, DIM_OUT=128, DIM_X=256, L=256, BATCH=8192, fp32.
#define NB 8192

// ---------- static_for helper (compile-time register indices) ----------
template <typename F, size_t... I>
__device__ __forceinline__ void sfor_impl(F&& f, std::index_sequence<I...>) {
  (f(std::integral_constant<int, (int)I>{}), ...);
}
template <int N, typename F>
__device__ __forceinline__ void sfor(F&& f) {
  sfor_impl((F&&)f, std::make_index_sequence<N>{});
}

// packed-column-triangle offset: column li holds D[l2][li], l2=li+1..63, padded to x4
constexpr int coff(int li) {
  int o = 0;
  for (int j = 0; j < li; ++j) o += ((63 - j) + 3) & ~3;
  return o;
}
#define CPACK_STRIDE 2176  // > coff(63), float4-aligned

// fast tanh: 1 - 2/(exp(2x)+1). Correct limits at +/-inf.
__device__ __forceinline__ float fast_tanh(float x) {
  const float e = __expf(2.0f * x);
  return 1.0f - 2.0f / (e + 1.0f);
}

// =================== device phase functions (verified bodies) ===================

__device__ void dev_prep(const float* __restrict__ x, const float* __restrict__ C1,
                         const float* __restrict__ Fm, const float* __restrict__ Lam,
                         float* __restrict__ cx, float* __restrict__ xF,
                         float* __restrict__ rLam, int t) {
  float s1 = 0.f, s2 = 0.f;
  for (int i = 0; i < 256; ++i) {
    const float xi = x[i];
    s1 += C1[t * 256 + i] * xi;
    s2 += Fm[t * 256 + i] * xi;
  }
  cx[t] = s1;
  xF[t] = s2;
  rLam[t] = 1.0f / Lam[t];
}

__device__ void dev_pack(const float* __restrict__ D11, float* __restrict__ cpack,
                         int t) {
  const int c = t >> 6;
  const int lane = t & 63;
  int off = 0;
  for (int li = 0; li < 63; ++li) {
    if (lane < 63 - li)
      cpack[c * CPACK_STRIDE + off + lane] =
          D11[(c * 64 + li + 1 + lane) * 256 + (c * 64 + li)];
    off += ((63 - li) + 3) & ~3;
  }
}

// blocked-panel GJ inverse of 128x128, streaming phase-2 (verified in R8)
__device__ void dev_inv(const float* __restrict__ srcT, int ld,
                        float* __restrict__ dstT, int tid, float* sm) {
  float* Pc = sm;               // [16][132] panel cols (col-major)
  float* MBt = sm + 16 * 132;   // [16][132] M transposed
  float* Ar = sm + 32 * 132;    // [16][132] old panel rows
  float* invD = sm + 48 * 132;  // [16][20]
  const int ti = tid >> 4, tj = tid & 15;
  const int R = ti * 8, C = tj * 8;
  float a[8][8];
#pragma unroll
  for (int i = 0; i < 8; ++i)
#pragma unroll
    for (int j = 0; j < 8; ++j) a[i][j] = srcT[(C + j) * ld + (R + i)];

  for (int s = 0; s < 8; ++s) {
    if ((tj >> 1) == s) {
      const int c0 = (tj & 1) * 8;
#pragma unroll
      for (int j = 0; j < 8; ++j)
#pragma unroll
        for (int i = 0; i < 8; ++i) Pc[(c0 + j) * 132 + R + i] = a[i][j];
    }
    if ((ti >> 1) == s) {
      const int r0 = (ti & 1) * 8;
#pragma unroll
      for (int i = 0; i < 8; ++i)
#pragma unroll
        for (int j = 0; j < 8; ++j) Ar[(r0 + i) * 132 + C + j] = a[i][j];
    }
    __syncthreads();

    if (tid < 16) {
      float q[16];
#pragma unroll
      for (int j = 0; j < 16; ++j) q[j] = Pc[j * 132 + s * 16 + tid];
#pragma unroll
      for (int kk = 0; kk < 16; ++kk) {
        float ps[16];
#pragma unroll
        for (int j = 0; j < 16; ++j) ps[j] = __shfl(q[j], kk, 16);
        const float piv = 1.0f / ps[kk];
#pragma unroll
        for (int j = 0; j < 16; ++j) ps[j] = (j == kk) ? piv : ps[j] * piv;
        const bool isP = (tid == kk);
        const float te = isP ? -1.0f : q[kk];
#pragma unroll
        for (int j = 0; j < 16; ++j) {
          const float base = (isP || j == kk) ? 0.0f : q[j];
          q[j] = base - te * ps[j];
        }
      }
#pragma unroll
      for (int j = 0; j < 16; ++j) invD[tid * 20 + j] = q[j];
    }
    __syncthreads();

    {
      const int r = tid & 127, h = tid >> 7;
      float mv[8];
      if ((r >> 4) == s) {
        const int rr = r & 15;
#pragma unroll
        for (int j = 0; j < 8; ++j) mv[j] = invD[rr * 20 + 8 * h + j];
      } else {
#pragma unroll
        for (int j = 0; j < 8; ++j) mv[j] = 0.f;
#pragma unroll
        for (int k = 0; k < 16; ++k) {
          const float pk = Pc[k * 132 + r];
          const float4 d0 = *(const float4*)&invD[k * 20 + 8 * h];
          const float4 d1 = *(const float4*)&invD[k * 20 + 8 * h + 4];
          mv[0] -= pk * d0.x; mv[1] -= pk * d0.y; mv[2] -= pk * d0.z; mv[3] -= pk * d0.w;
          mv[4] -= pk * d1.x; mv[5] -= pk * d1.y; mv[6] -= pk * d1.z; mv[7] -= pk * d1.w;
        }
      }
#pragma unroll
      for (int j = 0; j < 8; ++j) MBt[(8 * h + j) * 132 + r] = mv[j];
    }
    __syncthreads();

    if ((tj >> 1) == s) {
      const int c0 = (tj & 1) * 8;
#pragma unroll
      for (int j = 0; j < 8; ++j)
#pragma unroll
        for (int i = 0; i < 8; ++i) a[i][j] = MBt[(c0 + j) * 132 + R + i];
    } else {
      if ((ti >> 1) == s) {
#pragma unroll
        for (int i = 0; i < 8; ++i)
#pragma unroll
          for (int j = 0; j < 8; ++j) a[i][j] = 0.f;
      }
#pragma unroll
      for (int kk = 0; kk < 16; ++kk) {
        const float4 m0 = *(const float4*)&MBt[kk * 132 + R];
        const float4 m1 = *(const float4*)&MBt[kk * 132 + R + 4];
        const float4 p0 = *(const float4*)&Ar[kk * 132 + C];
        const float4 p1 = *(const float4*)&Ar[kk * 132 + C + 4];
        const float mi[8] = {m0.x, m0.y, m0.z, m0.w, m1.x, m1.y, m1.z, m1.w};
        const float pj[8] = {p0.x, p0.y, p0.z, p0.w, p1.x, p1.y, p1.z, p1.w};
#pragma unroll
        for (int i = 0; i < 8; ++i)
#pragma unroll
          for (int j = 0; j < 8; ++j) a[i][j] += mi[i] * pj[j];
      }
    }
    __syncthreads();
  }
#pragma unroll
  for (int i = 0; i < 8; ++i)
#pragma unroll
    for (int j = 0; j < 8; ++j) dstT[(C + j) * 128 + (R + i)] = a[i][j];
}

__device__ void dev_T(const float* __restrict__ u, float* __restrict__ vw, int bid,
                      int t, float* sm) {
  float* buf = sm;  // 64*65
  const int b0 = bid * 64;
#pragma unroll
  for (int h = 0; h < 2; ++h) {
#pragma unroll
    for (int q = 0; q < 16; ++q) {
      const int idx = q * 256 + t;
      const int bl = idx >> 6;
      const int i2 = idx & 63;
      buf[i2 * 65 + bl] = u[(b0 + bl) * 128 + 64 * h + i2];
    }
    __syncthreads();
#pragma unroll
    for (int q = 0; q < 16; ++q) {
      const int idx = q * 256 + t;
      const int i2 = idx >> 6;
      const int bl = idx & 63;
      vw[(256 + 64 * h + i2) * NB + b0 + bl] = buf[i2 * 65 + bl];
    }
    __syncthreads();
  }
}

__device__ void dev_du(const float* __restrict__ D12, const float* __restrict__ cx,
                       float* __restrict__ vw, int bid, int t, float* sm) {
  float* Dl = sm;  // 8*128
  const int bx = bid & 7;
  const int l0 = (bid >> 3) * 8;
#pragma unroll
  for (int q = 0; q < 4; ++q) Dl[q * 256 + t] = D12[l0 * 128 + q * 256 + t];
  __syncthreads();
  const float4* vw4 = (const float4*)vw;
  float4* vw4o = (float4*)vw;
  const int b4 = bx * 256 + t;
  float4 acc[8];
#pragma unroll
  for (int j = 0; j < 8; ++j) {
    const float cj = cx[l0 + j];
    acc[j] = make_float4(cj, cj, cj, cj);
  }
#pragma unroll 4
  for (int i = 0; i < 128; ++i) {
    const float4 wv = vw4[(256 + i) * 2048 + b4];
#pragma unroll
    for (int j = 0; j < 8; ++j) {
      const float d = Dl[j * 128 + i];
      acc[j].x += d * wv.x;
      acc[j].y += d * wv.y;
      acc[j].z += d * wv.z;
      acc[j].w += d * wv.w;
    }
  }
#pragma unroll
  for (int j = 0; j < 8; ++j) vw4o[(l0 + j) * 2048 + b4] = acc[j];
}

// W (TRANSPOSED: Wt[j][i] = W[i][j]) and z1  (A = E^T, c = C2^T)
__device__ void dev_WZ(const float* __restrict__ E, const float* __restrict__ C2,
                       const float* __restrict__ inv1T, float* __restrict__ Wt,
                       float* __restrict__ z1, int gid) {
  const int half = gid >> 14;
  const int idx = gid & 16383;
  const int j = idx >> 7;   // wave-uniform
  const int i = idx & 127;  // lane
  float s = 0.f;
  if (half == 0) {
    for (int m = 0; m < 128; ++m) s += inv1T[m * 128 + i] * E[(128 + j) * 256 + m];
    Wt[j * 128 + i] = s;  // coalesced store of W^T
  } else {
    for (int m = 0; m < 128; ++m) s += inv1T[m * 128 + i] * C2[j * 256 + m];
    z1[i * 128 + j] = s;
  }
}

// c2p = c2 - A21 z1 (extracted from verified dev_SC)
__device__ void dev_c2p(const float* __restrict__ E, const float* __restrict__ C2,
                        const float* __restrict__ z1, float* __restrict__ c2p,
                        int gid) {
  const int i = gid >> 7;   // wave-uniform
  const int o = gid & 127;  // lane
  float s = C2[o * 256 + 128 + i];
  for (int m = 0; m < 128; ++m) s -= E[m * 256 + 128 + i] * z1[m * 128 + o];
  c2p[i * 128 + o] = s;
}

// S^T = (A22 - A21 W)^T built by ONE block, then inv(S) by the same block
__device__ void dev_Sinv(const float* __restrict__ E, const float* __restrict__ Wt,
                         float* __restrict__ STt, float* __restrict__ inv2T, int t,
                         float* sm) {
  for (int q = 0; q < 64; ++q) {
    const int idx = q * 256 + t;
    const int jj = idx >> 7;  // wave-uniform
    const int i = idx & 127;  // lane
    float s = E[(128 + jj) * 256 + 128 + i];
    for (int m = 0; m < 128; ++m) s -= E[m * 256 + 128 + i] * Wt[jj * 128 + m];
    STt[jj * 128 + i] = s;
  }
  __threadfence_block();
  __syncthreads();
  dev_inv(STt, 128, inv2T, t, sm);
}

// merged G2+G1: block bo owns o-columns {2bo, 2bo+1}; g2 stashed in LDS for g1
__device__ void dev_G21(const float* __restrict__ inv2T, const float* __restrict__ c2p,
                        const float* __restrict__ Wt, const float* __restrict__ z1,
                        float* __restrict__ g2, float* __restrict__ g1, int bo, int t,
                        float* g2loc /* [2][128] */) {
  const int i = t & 127;   // lane
  const int oh = t >> 7;   // 0/1
  const int o = 2 * bo + oh;
  // phase A: g2[i][o] = sum_m inv(S)[i][m] * c2p[m][o]
  float s = 0.f;
  for (int m = 0; m < 128; ++m) s += inv2T[m * 128 + i] * c2p[m * 128 + o];
  g2loc[oh * 128 + i] = s;
  g2[i * 128 + o] = s;
  __syncthreads();
  // phase B: g1[i][o] = z1[i][o] - sum_m W[i][m] * g2[m][o];  W[i][m] = Wt[m][i]
  float s1 = z1[i * 128 + o];
  for (int m = 0; m < 128; ++m) s1 -= Wt[m * 128 + i] * g2loc[oh * 128 + m];
  g1[i * 128 + o] = s1;
}

__device__ void dev_R(const float* __restrict__ B1, const float* __restrict__ B2,
                      const float* __restrict__ D21, const float* __restrict__ D22,
                      const float* __restrict__ g1, const float* __restrict__ g2,
                      const float* __restrict__ xF, float* __restrict__ R,
                      float* __restrict__ y0, int gid) {
  if (gid < 32768) {
    const int o = gid >> 8;
    const int l = gid & 255;
    float s = D21[o * 256 + l];
    for (int m = 0; m < 128; ++m) {
      s += g1[m * 128 + o] * B1[m * 256 + l];
      s += g2[m * 128 + o] * B1[(128 + m) * 256 + l];
    }
    R[o * 384 + l] = s;
  } else if (gid < 49152) {
    const int t2 = gid - 32768;
    const int o = t2 >> 7;
    const int i = t2 & 127;
    float s = D22[o * 128 + i];
    for (int m = 0; m < 128; ++m) {
      s += g1[m * 128 + o] * B2[m * 128 + i];
      s += g2[m * 128 + o] * B2[(128 + m) * 128 + i];
    }
    R[o * 384 + 256 + i] = s;
  } else if (gid < 49280) {
    const int o = gid - 49152;
    float s = 0.f;
    for (int m = 0; m < 128; ++m) {
      s += g1[m * 128 + o] * xF[m];
      s += g2[m * 128 + o] * xF[128 + m];
    }
    y0[o] = s;
  }
}

// ---------- FULL scan, one kernel, no grid sync (recurrence is per-column!) ------
// Per thread (1 batch column): for each 64-chunk: load v-inits, add left-looking
// cross-chunk contributions (own prior w from global, D11 wave-uniform scalars),
// then the verified 64-step register scan.
__device__ void dev_scanall(const float* __restrict__ cpack,
                            const float* __restrict__ rLam,
                            const float* __restrict__ D11, float* vw, int bid,
                            int t) {
  const int b = bid * 256 + t;
  for (int c = 0; c < 4; ++c) {
    const int l0 = c * 64;
    const float4* cp4 = (const float4*)(cpack + c * CPACK_STRIDE);
    float v[64];
#pragma unroll
    for (int li = 0; li < 64; ++li) v[li] = vw[(l0 + li) * NB + b];
    // left-looking cross-chunk update: v[li] += sum_{k<l0} D11[l0+li][k] * w[k][b]
    for (int k = 0; k < l0; ++k) {
      const float wk = vw[k * NB + b];  // own column, coalesced across lanes
#pragma unroll
      for (int li = 0; li < 64; ++li)
        v[li] += D11[(l0 + li) * 256 + k] * wk;  // wave-uniform -> scalar load
    }
    // in-chunk right-looking register scan (verified R5-R8 body)
    sfor<64>([&](auto LI) {
      constexpr int li = decltype(LI)::value;
      const float w = fast_tanh(v[li] * rLam[l0 + li]);
      vw[(l0 + li) * NB + b] = w;
      constexpr int n = 63 - li;
      constexpr int off4 = coff(li) / 4;
      sfor<(n + 3) / 4>([&](auto Q) {
        constexpr int q = decltype(Q)::value;
        const float4 d = cp4[off4 + q];
        if constexpr (4 * q + 0 < n) v[li + 1 + 4 * q + 0] += d.x * w;
        if constexpr (4 * q + 1 < n) v[li + 1 + 4 * q + 1] += d.y * w;
        if constexpr (4 * q + 2 < n) v[li + 1 + 4 * q + 2] += d.z * w;
        if constexpr (4 * q + 3 < n) v[li + 1 + 4 * q + 3] += d.w * w;
      });
    });
  }
}

__device__ void dev_ky(const float* __restrict__ vw, const float* __restrict__ R,
                       const float* __restrict__ y0, float* __restrict__ y, int bid,
                       int tid, float* sm) {
  float* Rl = sm;  // 1536
  const int gx = bid & 7;   // b-tile (XCD-aligned)
  const int gy = bid >> 3;  // o-tile
  const int o0 = gy * 4;
#pragma unroll
  for (int q = 0; q < 6; ++q) Rl[q * 256 + tid] = R[o0 * 384 + q * 256 + tid];
  __syncthreads();
  const float4* vw4 = (const float4*)vw;
  const int b4 = gx * 256 + tid;
  float acc[4][4];
#pragma unroll
  for (int j = 0; j < 4; ++j) {
    const float y0j = y0[o0 + j];
#pragma unroll
    for (int bi = 0; bi < 4; ++bi) acc[bi][j] = y0j;
  }
#pragma unroll 4
  for (int k = 0; k < 384; k += 4) {
    const float4 w0 = vw4[(k + 0) * 2048 + b4];
    const float4 w1 = vw4[(k + 1) * 2048 + b4];
    const float4 w2 = vw4[(k + 2) * 2048 + b4];
    const float4 w3 = vw4[(k + 3) * 2048 + b4];
#pragma unroll
    for (int j = 0; j < 4; ++j) {
      const float4 r = *(const float4*)&Rl[j * 384 + k];
      acc[0][j] += r.x * w0.x + r.y * w1.x + r.z * w2.x + r.w * w3.x;
      acc[1][j] += r.x * w0.y + r.y * w1.y + r.z * w2.y + r.w * w3.y;
      acc[2][j] += r.x * w0.z + r.y * w1.z + r.z * w2.z + r.w * w3.z;
      acc[3][j] += r.x * w0.w + r.y * w1.w + r.z * w2.w + r.w * w3.w;
    }
  }
  const int b0 = b4 * 4;
#pragma unroll
  for (int bi = 0; bi < 4; ++bi) {
    *(float4*)&y[(b0 + bi) * 128 + o0] =
        make_float4(acc[bi][0], acc[bi][1], acc[bi][2], acc[bi][3]);
  }
}

// =================== mega kernels (6 launches, 5 junctions) ===================

__global__ __launch_bounds__(256) void mega1(const float* u, const float* x,
                                             const float* C1, const float* Fm,
                                             const float* Lam, const float* D11,
                                             const float* E, float* vw, float* cx,
                                             float* xF, float* rLam, float* cpack,
                                             float* inv1T) {
  __shared__ __align__(16) float sm[6656];
  const int bid = blockIdx.x;
  const int t = threadIdx.x;
  if (bid < 128) dev_T(u, vw, bid, t, sm);
  else if (bid == 128) dev_prep(x, C1, Fm, Lam, cx, xF, rLam, t);
  else if (bid == 129) dev_pack(D11, cpack, t);
  else dev_inv(E, 256, inv1T, t, sm);  // bid == 130
}

__global__ __launch_bounds__(256) void mega2(const float* D12, const float* cx,
                                             float* vw, const float* E,
                                             const float* C2, const float* inv1T,
                                             float* Wt, float* z1) {
  __shared__ __align__(16) float sm[1024];
  const int bid = blockIdx.x;
  const int t = threadIdx.x;
  if (bid < 256) dev_du(D12, cx, vw, bid, t, sm);
  else dev_WZ(E, C2, inv1T, Wt, z1, (bid - 256) * 256 + t);
}

__global__ __launch_bounds__(256) void mega3(const float* cpack, const float* rLam,
                                             const float* D11, float* vw,
                                             const float* E, const float* C2,
                                             const float* Wt, const float* z1,
                                             float* c2p, float* STt, float* inv2T) {
  __shared__ __align__(16) float sm[6656];
  const int bid = blockIdx.x;
  const int t = threadIdx.x;
  if (bid < 32) dev_scanall(cpack, rLam, D11, vw, bid, t);
  else if (bid < 96) dev_c2p(E, C2, z1, c2p, (bid - 32) * 256 + t);
  else dev_Sinv(E, Wt, STt, inv2T, t, sm);  // bid == 96
}

__global__ __launch_bounds__(256) void mega4(const float* inv2T, const float* c2p,
                                             const float* Wt, const float* z1,
                                             float* g2, float* g1) {
  __shared__ float g2loc[2 * 128];
  dev_G21(inv2T, c2p, Wt, z1, g2, g1, blockIdx.x, threadIdx.x, g2loc);
}

__global__ __launch_bounds__(256) void mega5(const float* B1, const float* B2,
                                             const float* D21, const float* D22,
                                             const float* g1, const float* g2,
                                             const float* xF, float* R, float* y0) {
  dev_R(B1, B2, D21, D22, g1, g2, xF, R, y0, blockIdx.x * 256 + threadIdx.x);
}

__global__ __launch_bounds__(256) void mega6(const float* vw, const float* R,
                                             const float* y0, float* y) {
  __shared__ __align__(16) float sm[1536];
  dev_ky(vw, R, y0, y, blockIdx.x, threadIdx.x, sm);
}

extern "C" void kernel_launch(void* const* d_in, const int* in_sizes, int n_in,
                              void* d_out, int out_size, void* d_ws, size_t ws_size,
                              hipStream_t stream) {
  const float* u   = (const float*)d_in[0];
  const float* x   = (const float*)d_in[1];
  const float* Fm  = (const float*)d_in[2];
  const float* B1  = (const float*)d_in[3];
  const float* B2  = (const float*)d_in[4];
  const float* C1  = (const float*)d_in[5];
  const float* C2  = (const float*)d_in[6];
  const float* D11 = (const float*)d_in[7];
  const float* D12 = (const float*)d_in[8];
  const float* D21 = (const float*)d_in[9];
  const float* D22 = (const float*)d_in[10];
  const float* E   = (const float*)d_in[11];
  const float* Lam = (const float*)d_in[12];
  float* y = (float*)d_out;

  float* F = (float*)d_ws;  // ~13.4 MB used
  float* vw    = F;         // 384*8192 (rows 256..383 = u^T)
  float* SMb   = F + 384 * NB;
  float* inv1T = SMb;            // 16384
  float* Wt    = SMb + 16384;    // W transposed
  float* z1    = SMb + 32768;
  float* STt   = SMb + 49152;
  float* c2p   = SMb + 65536;
  float* inv2T = SMb + 81920;
  float* g2    = SMb + 98304;
  float* g1    = SMb + 114688;
  float* Rm    = SMb + 131072;   // 128*384
  float* y0v   = SMb + 180224;   // 128
  float* cx    = SMb + 180352;   // 256
  float* xF    = SMb + 180608;   // 256
  float* rLam  = SMb + 180864;   // 256
  float* cpack = SMb + 181120;   // 4*2176

  mega1<<<131, 256, 0, stream>>>(u, x, C1, Fm, Lam, D11, E, vw, cx, xF, rLam,
                                 cpack, inv1T);
  mega2<<<384, 256, 0, stream>>>(D12, cx, vw, E, C2, inv1T, Wt, z1);
  mega3<<<97, 256, 0, stream>>>(cpack, rLam, D11, vw, E, C2, Wt, z1, c2p, STt,
                                inv2T);
  mega4<<<64, 256, 0, stream>>>(inv2T, c2p, Wt, z1, g2, g1);
  mega5<<<193, 256, 0, stream>>>(B1, B2, D21, D22, g1, g2, xF, Rm, y0v);
  mega6<<<256, 256, 0, stream>>>(vw, Rm, y0v, y);
}

// Round 10
// 589.627 us; speedup vs baseline: 1.8093x; 1.8093x over previous
//
#include <hip/hip_runtime.h>
#include <utility>

// Problem constants: DIM_IN=128, DIM_OUT=128, DIM_X=256, L=256, BATCH=8192, fp32.
#define NB 8192

// ---------- static_for helper (compile-time register indices) ----------
template <typename F, size_t... I>
__device__ __forceinline__ void sfor_impl(F&& f, std::index_sequence<I...>) {
  (f(std::integral_constant<int, (int)I>{}), ...);
}
template <int N, typename F>
__device__ __forceinline__ void sfor(F&& f) {
  sfor_impl((F&&)f, std::make_index_sequence<N>{});
}

// packed-column-triangle offset: column li holds D[l2][li], l2=li+1..63, padded to x4
constexpr int coff(int li) {
  int o = 0;
  for (int j = 0; j < li; ++j) o += ((63 - j) + 3) & ~3;
  return o;
}
#define CPACK_STRIDE 2176  // > coff(63), float4-aligned

// fast tanh: 1 - 2/(exp(2x)+1). Correct limits at +/-inf.
__device__ __forceinline__ float fast_tanh(float x) {
  const float e = __expf(2.0f * x);
  return 1.0f - 2.0f / (e + 1.0f);
}

// =================== device phase functions (verified bodies) ===================

__device__ void dev_prep(const float* __restrict__ x, const float* __restrict__ C1,
                         const float* __restrict__ Fm, const float* __restrict__ Lam,
                         float* __restrict__ cx, float* __restrict__ xF,
                         float* __restrict__ rLam, int t) {
  float s1 = 0.f, s2 = 0.f;
  for (int i = 0; i < 256; ++i) {
    const float xi = x[i];
    s1 += C1[t * 256 + i] * xi;
    s2 += Fm[t * 256 + i] * xi;
  }
  cx[t] = s1;
  xF[t] = s2;
  rLam[t] = 1.0f / Lam[t];
}

__device__ void dev_pack(const float* __restrict__ D11, float* __restrict__ cpack,
                         int t) {
  const int c = t >> 6;
  const int lane = t & 63;
  int off = 0;
  for (int li = 0; li < 63; ++li) {
    if (lane < 63 - li)
      cpack[c * CPACK_STRIDE + off + lane] =
          D11[(c * 64 + li + 1 + lane) * 256 + (c * 64 + li)];
    off += ((63 - li) + 3) & ~3;
  }
}

// blocked-panel GJ inverse of 128x128, streaming phase-2 (verified R8/R9)
__device__ void dev_inv(const float* __restrict__ srcT, int ld,
                        float* __restrict__ dstT, int tid, float* sm) {
  float* Pc = sm;               // [16][132] panel cols (col-major)
  float* MBt = sm + 16 * 132;   // [16][132] M transposed
  float* Ar = sm + 32 * 132;    // [16][132] old panel rows
  float* invD = sm + 48 * 132;  // [16][20]
  const int ti = tid >> 4, tj = tid & 15;
  const int R = ti * 8, C = tj * 8;
  float a[8][8];
#pragma unroll
  for (int i = 0; i < 8; ++i)
#pragma unroll
    for (int j = 0; j < 8; ++j) a[i][j] = srcT[(C + j) * ld + (R + i)];

  for (int s = 0; s < 8; ++s) {
    if ((tj >> 1) == s) {
      const int c0 = (tj & 1) * 8;
#pragma unroll
      for (int j = 0; j < 8; ++j)
#pragma unroll
        for (int i = 0; i < 8; ++i) Pc[(c0 + j) * 132 + R + i] = a[i][j];
    }
    if ((ti >> 1) == s) {
      const int r0 = (ti & 1) * 8;
#pragma unroll
      for (int i = 0; i < 8; ++i)
#pragma unroll
        for (int j = 0; j < 8; ++j) Ar[(r0 + i) * 132 + C + j] = a[i][j];
    }
    __syncthreads();

    if (tid < 16) {
      float q[16];
#pragma unroll
      for (int j = 0; j < 16; ++j) q[j] = Pc[j * 132 + s * 16 + tid];
#pragma unroll
      for (int kk = 0; kk < 16; ++kk) {
        float ps[16];
#pragma unroll
        for (int j = 0; j < 16; ++j) ps[j] = __shfl(q[j], kk, 16);
        const float piv = 1.0f / ps[kk];
#pragma unroll
        for (int j = 0; j < 16; ++j) ps[j] = (j == kk) ? piv : ps[j] * piv;
        const bool isP = (tid == kk);
        const float te = isP ? -1.0f : q[kk];
#pragma unroll
        for (int j = 0; j < 16; ++j) {
          const float base = (isP || j == kk) ? 0.0f : q[j];
          q[j] = base - te * ps[j];
        }
      }
#pragma unroll
      for (int j = 0; j < 16; ++j) invD[tid * 20 + j] = q[j];
    }
    __syncthreads();

    {
      const int r = tid & 127, h = tid >> 7;
      float mv[8];
      if ((r >> 4) == s) {
        const int rr = r & 15;
#pragma unroll
        for (int j = 0; j < 8; ++j) mv[j] = invD[rr * 20 + 8 * h + j];
      } else {
#pragma unroll
        for (int j = 0; j < 8; ++j) mv[j] = 0.f;
#pragma unroll
        for (int k = 0; k < 16; ++k) {
          const float pk = Pc[k * 132 + r];
          const float4 d0 = *(const float4*)&invD[k * 20 + 8 * h];
          const float4 d1 = *(const float4*)&invD[k * 20 + 8 * h + 4];
          mv[0] -= pk * d0.x; mv[1] -= pk * d0.y; mv[2] -= pk * d0.z; mv[3] -= pk * d0.w;
          mv[4] -= pk * d1.x; mv[5] -= pk * d1.y; mv[6] -= pk * d1.z; mv[7] -= pk * d1.w;
        }
      }
#pragma unroll
      for (int j = 0; j < 8; ++j) MBt[(8 * h + j) * 132 + r] = mv[j];
    }
    __syncthreads();

    if ((tj >> 1) == s) {
      const int c0 = (tj & 1) * 8;
#pragma unroll
      for (int j = 0; j < 8; ++j)
#pragma unroll
        for (int i = 0; i < 8; ++i) a[i][j] = MBt[(c0 + j) * 132 + R + i];
    } else {
      if ((ti >> 1) == s) {
#pragma unroll
        for (int i = 0; i < 8; ++i)
#pragma unroll
          for (int j = 0; j < 8; ++j) a[i][j] = 0.f;
      }
#pragma unroll
      for (int kk = 0; kk < 16; ++kk) {
        const float4 m0 = *(const float4*)&MBt[kk * 132 + R];
        const float4 m1 = *(const float4*)&MBt[kk * 132 + R + 4];
        const float4 p0 = *(const float4*)&Ar[kk * 132 + C];
        const float4 p1 = *(const float4*)&Ar[kk * 132 + C + 4];
        const float mi[8] = {m0.x, m0.y, m0.z, m0.w, m1.x, m1.y, m1.z, m1.w};
        const float pj[8] = {p0.x, p0.y, p0.z, p0.w, p1.x, p1.y, p1.z, p1.w};
#pragma unroll
        for (int i = 0; i < 8; ++i)
#pragma unroll
          for (int j = 0; j < 8; ++j) a[i][j] += mi[i] * pj[j];
      }
    }
    __syncthreads();
  }
#pragma unroll
  for (int i = 0; i < 8; ++i)
#pragma unroll
    for (int j = 0; j < 8; ++j) dstT[(C + j) * 128 + (R + i)] = a[i][j];
}

__device__ void dev_T(const float* __restrict__ u, float* __restrict__ vw, int bid,
                      int t, float* sm) {
  float* buf = sm;  // 64*65
  const int b0 = bid * 64;
#pragma unroll
  for (int h = 0; h < 2; ++h) {
#pragma unroll
    for (int q = 0; q < 16; ++q) {
      const int idx = q * 256 + t;
      const int bl = idx >> 6;
      const int i2 = idx & 63;
      buf[i2 * 65 + bl] = u[(b0 + bl) * 128 + 64 * h + i2];
    }
    __syncthreads();
#pragma unroll
    for (int q = 0; q < 16; ++q) {
      const int idx = q * 256 + t;
      const int i2 = idx >> 6;
      const int bl = idx & 63;
      vw[(256 + 64 * h + i2) * NB + b0 + bl] = buf[i2 * 65 + bl];
    }
    __syncthreads();
  }
}

__device__ void dev_du(const float* __restrict__ D12, const float* __restrict__ cx,
                       float* __restrict__ vw, int bid, int t, float* sm) {
  float* Dl = sm;  // 8*128
  const int bx = bid & 7;
  const int l0 = (bid >> 3) * 8;
#pragma unroll
  for (int q = 0; q < 4; ++q) Dl[q * 256 + t] = D12[l0 * 128 + q * 256 + t];
  __syncthreads();
  const float4* vw4 = (const float4*)vw;
  float4* vw4o = (float4*)vw;
  const int b4 = bx * 256 + t;
  float4 acc[8];
#pragma unroll
  for (int j = 0; j < 8; ++j) {
    const float cj = cx[l0 + j];
    acc[j] = make_float4(cj, cj, cj, cj);
  }
#pragma unroll 4
  for (int i = 0; i < 128; ++i) {
    const float4 wv = vw4[(256 + i) * 2048 + b4];
#pragma unroll
    for (int j = 0; j < 8; ++j) {
      const float d = Dl[j * 128 + i];
      acc[j].x += d * wv.x;
      acc[j].y += d * wv.y;
      acc[j].z += d * wv.z;
      acc[j].w += d * wv.w;
    }
  }
#pragma unroll
  for (int j = 0; j < 8; ++j) vw4o[(l0 + j) * 2048 + b4] = acc[j];
}

// W (TRANSPOSED: Wt[j][i] = W[i][j]) and z1  (A = E^T, c = C2^T)
__device__ void dev_WZ(const float* __restrict__ E, const float* __restrict__ C2,
                       const float* __restrict__ inv1T, float* __restrict__ Wt,
                       float* __restrict__ z1, int gid) {
  const int half = gid >> 14;
  const int idx = gid & 16383;
  const int j = idx >> 7;   // wave-uniform
  const int i = idx & 127;  // lane
  float s = 0.f;
  if (half == 0) {
    for (int m = 0; m < 128; ++m) s += inv1T[m * 128 + i] * E[(128 + j) * 256 + m];
    Wt[j * 128 + i] = s;  // coalesced store of W^T
  } else {
    for (int m = 0; m < 128; ++m) s += inv1T[m * 128 + i] * C2[j * 256 + m];
    z1[i * 128 + j] = s;
  }
}

// c2p = c2 - A21 z1
__device__ void dev_c2p(const float* __restrict__ E, const float* __restrict__ C2,
                        const float* __restrict__ z1, float* __restrict__ c2p,
                        int gid) {
  const int i = gid >> 7;   // wave-uniform
  const int o = gid & 127;  // lane
  float s = C2[o * 256 + 128 + i];
  for (int m = 0; m < 128; ++m) s -= E[m * 256 + 128 + i] * z1[m * 128 + o];
  c2p[i * 128 + o] = s;
}

// S^T = (A22 - A21 W)^T built by ONE block, then inv(S) by the same block
__device__ void dev_Sinv(const float* __restrict__ E, const float* __restrict__ Wt,
                         float* __restrict__ STt, float* __restrict__ inv2T, int t,
                         float* sm) {
  for (int q = 0; q < 64; ++q) {
    const int idx = q * 256 + t;
    const int jj = idx >> 7;  // wave-uniform
    const int i = idx & 127;  // lane
    float s = E[(128 + jj) * 256 + 128 + i];
    for (int m = 0; m < 128; ++m) s -= E[m * 256 + 128 + i] * Wt[jj * 128 + m];
    STt[jj * 128 + i] = s;
  }
  __threadfence_block();
  __syncthreads();
  dev_inv(STt, 128, inv2T, t, sm);
}

// merged G2+G1: block bo owns o-columns {2bo, 2bo+1}; g2 stashed in LDS for g1
__device__ void dev_G21(const float* __restrict__ inv2T, const float* __restrict__ c2p,
                        const float* __restrict__ Wt, const float* __restrict__ z1,
                        float* __restrict__ g2, float* __restrict__ g1, int bo, int t,
                        float* g2loc /* [2][128] */) {
  const int i = t & 127;   // lane
  const int oh = t >> 7;   // 0/1
  const int o = 2 * bo + oh;
  float s = 0.f;
  for (int m = 0; m < 128; ++m) s += inv2T[m * 128 + i] * c2p[m * 128 + o];
  g2loc[oh * 128 + i] = s;
  g2[i * 128 + o] = s;
  __syncthreads();
  float s1 = z1[i * 128 + o];
  for (int m = 0; m < 128; ++m) s1 -= Wt[m * 128 + i] * g2loc[oh * 128 + m];
  g1[i * 128 + o] = s1;
}

__device__ void dev_R(const float* __restrict__ B1, const float* __restrict__ B2,
                      const float* __restrict__ D21, const float* __restrict__ D22,
                      const float* __restrict__ g1, const float* __restrict__ g2,
                      const float* __restrict__ xF, float* __restrict__ R,
                      float* __restrict__ y0, int gid) {
  if (gid < 32768) {
    const int o = gid >> 8;
    const int l = gid & 255;
    float s = D21[o * 256 + l];
    for (int m = 0; m < 128; ++m) {
      s += g1[m * 128 + o] * B1[m * 256 + l];
      s += g2[m * 128 + o] * B1[(128 + m) * 256 + l];
    }
    R[o * 384 + l] = s;
  } else if (gid < 49152) {
    const int t2 = gid - 32768;
    const int o = t2 >> 7;
    const int i = t2 & 127;
    float s = D22[o * 128 + i];
    for (int m = 0; m < 128; ++m) {
      s += g1[m * 128 + o] * B2[m * 128 + i];
      s += g2[m * 128 + o] * B2[(128 + m) * 128 + i];
    }
    R[o * 384 + 256 + i] = s;
  } else if (gid < 49280) {
    const int o = gid - 49152;
    float s = 0.f;
    for (int m = 0; m < 128; ++m) {
      s += g1[m * 128 + o] * xF[m];
      s += g2[m * 128 + o] * xF[128 + m];
    }
    y0[o] = s;
  }
}

// ---------- FULL scan, one kernel, no grid sync (recurrence is per-column) -------
// Cross-chunk update restructured ROW-major (R9's column-walk of scattered s_loads
// was the 820us bug): per earlier chunk c2, w-segment in registers (coalesced
// loads), D11 row segments as all-lane-broadcast float4 loads (cpack-proven
// pattern), accumulator half-chunk in LDS vbuf[32][256] (dynamic li OK, per-thread
// column -> no barriers, 2-way bank alias free). Scan itself: verified register
// body.
__device__ void dev_scanall(const float* __restrict__ cpack,
                            const float* __restrict__ rLam,
                            const float* __restrict__ D11, float* vw, int bid,
                            int t, float* vbuf /* 32*256 floats */) {
  const int b = bid * 256 + t;
  float v[64];
  float wseg[64];
  for (int c = 0; c < 4; ++c) {
    const int l0 = c * 64;
    if (c == 0) {
#pragma unroll
      for (int li = 0; li < 64; ++li) v[li] = vw[li * NB + b];
    } else {
      for (int h = 0; h < 2; ++h) {
        const int lh = l0 + 32 * h;
        for (int li = 0; li < 32; ++li) vbuf[li * 256 + t] = vw[(lh + li) * NB + b];
        for (int c2 = 0; c2 < c; ++c2) {
          const int k0 = c2 * 64;
#pragma unroll
          for (int k = 0; k < 64; ++k) wseg[k] = vw[(k0 + k) * NB + b];
          for (int li = 0; li < 32; ++li) {  // dynamic li: acc lives in LDS
            const float4* drow4 = (const float4*)(D11 + (lh + li) * 256 + k0);
            float s0 = 0.f, s1 = 0.f, s2 = 0.f, s3 = 0.f;
#pragma unroll
            for (int q = 0; q < 16; ++q) {
              const float4 d = drow4[q];  // all-lane broadcast, L1/L2-hot
              s0 += d.x * wseg[4 * q + 0];
              s1 += d.y * wseg[4 * q + 1];
              s2 += d.z * wseg[4 * q + 2];
              s3 += d.w * wseg[4 * q + 3];
            }
            vbuf[li * 256 + t] += (s0 + s1) + (s2 + s3);
          }
        }
        if (h == 0) {
          sfor<32>([&](auto LI) { v[decltype(LI)::value] = vbuf[decltype(LI)::value * 256 + t]; });
        } else {
          sfor<32>([&](auto LI) { v[32 + decltype(LI)::value] = vbuf[decltype(LI)::value * 256 + t]; });
        }
      }
    }
    // in-chunk right-looking register scan (verified R5-R9 body)
    const float4* cp4 = (const float4*)(cpack + c * CPACK_STRIDE);
    sfor<64>([&](auto LI) {
      constexpr int li = decltype(LI)::value;
      const float w = fast_tanh(v[li] * rLam[l0 + li]);
      vw[(l0 + li) * NB + b] = w;
      constexpr int n = 63 - li;
      constexpr int off4 = coff(li) / 4;
      sfor<(n + 3) / 4>([&](auto Q) {
        constexpr int q = decltype(Q)::value;
        const float4 d = cp4[off4 + q];
        if constexpr (4 * q + 0 < n) v[li + 1 + 4 * q + 0] += d.x * w;
        if constexpr (4 * q + 1 < n) v[li + 1 + 4 * q + 1] += d.y * w;
        if constexpr (4 * q + 2 < n) v[li + 1 + 4 * q + 2] += d.z * w;
        if constexpr (4 * q + 3 < n) v[li + 1 + 4 * q + 3] += d.w * w;
      });
    });
  }
}

__device__ void dev_ky(const float* __restrict__ vw, const float* __restrict__ R,
                       const float* __restrict__ y0, float* __restrict__ y, int bid,
                       int tid, float* sm) {
  float* Rl = sm;  // 1536
  const int gx = bid & 7;   // b-tile (XCD-aligned)
  const int gy = bid >> 3;  // o-tile
  const int o0 = gy * 4;
#pragma unroll
  for (int q = 0; q < 6; ++q) Rl[q * 256 + tid] = R[o0 * 384 + q * 256 + tid];
  __syncthreads();
  const float4* vw4 = (const float4*)vw;
  const int b4 = gx * 256 + tid;
  float acc[4][4];
#pragma unroll
  for (int j = 0; j < 4; ++j) {
    const float y0j = y0[o0 + j];
#pragma unroll
    for (int bi = 0; bi < 4; ++bi) acc[bi][j] = y0j;
  }
#pragma unroll 4
  for (int k = 0; k < 384; k += 4) {
    const float4 w0 = vw4[(k + 0) * 2048 + b4];
    const float4 w1 = vw4[(k + 1) * 2048 + b4];
    const float4 w2 = vw4[(k + 2) * 2048 + b4];
    const float4 w3 = vw4[(k + 3) * 2048 + b4];
#pragma unroll
    for (int j = 0; j < 4; ++j) {
      const float4 r = *(const float4*)&Rl[j * 384 + k];
      acc[0][j] += r.x * w0.x + r.y * w1.x + r.z * w2.x + r.w * w3.x;
      acc[1][j] += r.x * w0.y + r.y * w1.y + r.z * w2.y + r.w * w3.y;
      acc[2][j] += r.x * w0.z + r.y * w1.z + r.z * w2.z + r.w * w3.z;
      acc[3][j] += r.x * w0.w + r.y * w1.w + r.z * w2.w + r.w * w3.w;
    }
  }
  const int b0 = b4 * 4;
#pragma unroll
  for (int bi = 0; bi < 4; ++bi) {
    *(float4*)&y[(b0 + bi) * 128 + o0] =
        make_float4(acc[bi][0], acc[bi][1], acc[bi][2], acc[bi][3]);
  }
}

// =================== mega kernels (6 launches, 5 junctions) ===================

__global__ __launch_bounds__(256) void mega1(const float* u, const float* x,
                                             const float* C1, const float* Fm,
                                             const float* Lam, const float* D11,
                                             const float* E, float* vw, float* cx,
                                             float* xF, float* rLam, float* cpack,
                                             float* inv1T) {
  __shared__ __align__(16) float sm[6656];
  const int bid = blockIdx.x;
  const int t = threadIdx.x;
  if (bid < 128) dev_T(u, vw, bid, t, sm);
  else if (bid == 128) dev_prep(x, C1, Fm, Lam, cx, xF, rLam, t);
  else if (bid == 129) dev_pack(D11, cpack, t);
  else dev_inv(E, 256, inv1T, t, sm);  // bid == 130
}

__global__ __launch_bounds__(256) void mega2(const float* D12, const float* cx,
                                             float* vw, const float* E,
                                             const float* C2, const float* inv1T,
                                             float* Wt, float* z1) {
  __shared__ __align__(16) float sm[1024];
  const int bid = blockIdx.x;
  const int t = threadIdx.x;
  if (bid < 256) dev_du(D12, cx, vw, bid, t, sm);
  else dev_WZ(E, C2, inv1T, Wt, z1, (bid - 256) * 256 + t);
}

__global__ __launch_bounds__(256) void mega3(const float* cpack, const float* rLam,
                                             const float* D11, float* vw,
                                             const float* E, const float* C2,
                                             const float* Wt, const float* z1,
                                             float* c2p, float* STt, float* inv2T) {
  __shared__ __align__(16) float smu[8192];  // union: vbuf (32 KB) / Sinv sm (26 KB)
  const int bid = blockIdx.x;
  const int t = threadIdx.x;
  if (bid < 32) dev_scanall(cpack, rLam, D11, vw, bid, t, smu);
  else if (bid < 96) dev_c2p(E, C2, z1, c2p, (bid - 32) * 256 + t);
  else dev_Sinv(E, Wt, STt, inv2T, t, smu);  // bid == 96
}

__global__ __launch_bounds__(256) void mega4(const float* inv2T, const float* c2p,
                                             const float* Wt, const float* z1,
                                             float* g2, float* g1) {
  __shared__ float g2loc[2 * 128];
  dev_G21(inv2T, c2p, Wt, z1, g2, g1, blockIdx.x, threadIdx.x, g2loc);
}

__global__ __launch_bounds__(256) void mega5(const float* B1, const float* B2,
                                             const float* D21, const float* D22,
                                             const float* g1, const float* g2,
                                             const float* xF, float* R, float* y0) {
  dev_R(B1, B2, D21, D22, g1, g2, xF, R, y0, blockIdx.x * 256 + threadIdx.x);
}

__global__ __launch_bounds__(256) void mega6(const float* vw, const float* R,
                                             const float* y0, float* y) {
  __shared__ __align__(16) float sm[1536];
  dev_ky(vw, R, y0, y, blockIdx.x, threadIdx.x, sm);
}

extern "C" void kernel_launch(void* const* d_in, const int* in_sizes, int n_in,
                              void* d_out, int out_size, void* d_ws, size_t ws_size,
                              hipStream_t stream) {
  const float* u   = (const float*)d_in[0];
  const float* x   = (const float*)d_in[1];
  const float* Fm  = (const float*)d_in[2];
  const float* B1  = (const float*)d_in[3];
  const float* B2  = (const float*)d_in[4];
  const float* C1  = (const float*)d_in[5];
  const float* C2  = (const float*)d_in[6];
  const float* D11 = (const float*)d_in[7];
  const float* D12 = (const float*)d_in[8];
  const float* D21 = (const float*)d_in[9];
  const float* D22 = (const float*)d_in[10];
  const float* E   = (const float*)d_in[11];
  const float* Lam = (const float*)d_in[12];
  float* y = (float*)d_out;

  float* F = (float*)d_ws;  // ~13.4 MB used
  float* vw    = F;         // 384*8192 (rows 256..383 = u^T)
  float* SMb   = F + 384 * NB;
  float* inv1T = SMb;            // 16384
  float* Wt    = SMb + 16384;    // W transposed
  float* z1    = SMb + 32768;
  float* STt   = SMb + 49152;
  float* c2p   = SMb + 65536;
  float* inv2T = SMb + 81920;
  float* g2    = SMb + 98304;
  float* g1    = SMb + 114688;
  float* Rm    = SMb + 131072;   // 128*384
  float* y0v   = SMb + 180224;   // 128
  float* cx    = SMb + 180352;   // 256
  float* xF    = SMb + 180608;   // 256
  float* rLam  = SMb + 180864;   // 256
  float* cpack = SMb + 181120;   // 4*2176

  mega1<<<131, 256, 0, stream>>>(u, x, C1, Fm, Lam, D11, E, vw, cx, xF, rLam,
                                 cpack, inv1T);
  mega2<<<384, 256, 0, stream>>>(D12, cx, vw, E, C2, inv1T, Wt, z1);
  mega3<<<97, 256, 0, stream>>>(cpack, rLam, D11, vw, E, C2, Wt, z1, c2p, STt,
                                inv2T);
  mega4<<<64, 256, 0, stream>>>(inv2T, c2p, Wt, z1, g2, g1);
  mega5<<<193, 256, 0, stream>>>(B1, B2, D21, D22, g1, g2, xF, Rm, y0v);
  mega6<<<256, 256, 0, stream>>>(vw, Rm, y0v, y);
}

// Round 11
// 566.477 us; speedup vs baseline: 1.8832x; 1.0409x over previous
//
#include <hip/hip_runtime.h>
#include <utility>

// Problem constants: DIM_IN=128, DIM_OUT=128, DIM_X=256, L=256, BATCH=8192, fp32.
#define NB 8192

// ---------- static_for helper (compile-time register indices) ----------
template <typename F, size_t... I>
__device__ __forceinline__ void sfor_impl(F&& f, std::index_sequence<I...>) {
  (f(std::integral_constant<int, (int)I>{}), ...);
}
template <int N, typename F>
__device__ __forceinline__ void sfor(F&& f) {
  sfor_impl((F&&)f, std::make_index_sequence<N>{});
}

// packed-column-triangle offset: column li holds D[l2][li], l2=li+1..63, padded to x4
constexpr int coff(int li) {
  int o = 0;
  for (int j = 0; j < li; ++j) o += ((63 - j) + 3) & ~3;
  return o;
}
#define CPACK_STRIDE 2176  // > coff(63), float4-aligned

// fast tanh: 1 - 2/(exp(2x)+1). Correct limits at +/-inf.
__device__ __forceinline__ float fast_tanh(float x) {
  const float e = __expf(2.0f * x);
  return 1.0f - 2.0f / (e + 1.0f);
}

// =================== device phase functions (verified bodies) ===================

__device__ void dev_prep(const float* __restrict__ x, const float* __restrict__ C1,
                         const float* __restrict__ Fm, const float* __restrict__ Lam,
                         float* __restrict__ cx, float* __restrict__ xF,
                         float* __restrict__ rLam, int t) {
  float s1 = 0.f, s2 = 0.f;
  for (int i = 0; i < 256; ++i) {
    const float xi = x[i];
    s1 += C1[t * 256 + i] * xi;
    s2 += Fm[t * 256 + i] * xi;
  }
  cx[t] = s1;
  xF[t] = s2;
  rLam[t] = 1.0f / Lam[t];
}

__device__ void dev_pack(const float* __restrict__ D11, float* __restrict__ cpack,
                         int t) {
  const int c = t >> 6;
  const int lane = t & 63;
  int off = 0;
  for (int li = 0; li < 63; ++li) {
    if (lane < 63 - li)
      cpack[c * CPACK_STRIDE + off + lane] =
          D11[(c * 64 + li + 1 + lane) * 256 + (c * 64 + li)];
    off += ((63 - li) + 3) & ~3;
  }
}

// blocked-panel GJ inverse of 128x128, streaming phase-2 (verified R8-R10)
__device__ void dev_inv(const float* __restrict__ srcT, int ld,
                        float* __restrict__ dstT, int tid, float* sm) {
  float* Pc = sm;               // [16][132] panel cols (col-major)
  float* MBt = sm + 16 * 132;   // [16][132] M transposed
  float* Ar = sm + 32 * 132;    // [16][132] old panel rows
  float* invD = sm + 48 * 132;  // [16][20]
  const int ti = tid >> 4, tj = tid & 15;
  const int R = ti * 8, C = tj * 8;
  float a[8][8];
#pragma unroll
  for (int i = 0; i < 8; ++i)
#pragma unroll
    for (int j = 0; j < 8; ++j) a[i][j] = srcT[(C + j) * ld + (R + i)];

  for (int s = 0; s < 8; ++s) {
    if ((tj >> 1) == s) {
      const int c0 = (tj & 1) * 8;
#pragma unroll
      for (int j = 0; j < 8; ++j)
#pragma unroll
        for (int i = 0; i < 8; ++i) Pc[(c0 + j) * 132 + R + i] = a[i][j];
    }
    if ((ti >> 1) == s) {
      const int r0 = (ti & 1) * 8;
#pragma unroll
      for (int i = 0; i < 8; ++i)
#pragma unroll
        for (int j = 0; j < 8; ++j) Ar[(r0 + i) * 132 + C + j] = a[i][j];
    }
    __syncthreads();

    if (tid < 16) {
      float q[16];
#pragma unroll
      for (int j = 0; j < 16; ++j) q[j] = Pc[j * 132 + s * 16 + tid];
#pragma unroll
      for (int kk = 0; kk < 16; ++kk) {
        float ps[16];
#pragma unroll
        for (int j = 0; j < 16; ++j) ps[j] = __shfl(q[j], kk, 16);
        const float piv = 1.0f / ps[kk];
#pragma unroll
        for (int j = 0; j < 16; ++j) ps[j] = (j == kk) ? piv : ps[j] * piv;
        const bool isP = (tid == kk);
        const float te = isP ? -1.0f : q[kk];
#pragma unroll
        for (int j = 0; j < 16; ++j) {
          const float base = (isP || j == kk) ? 0.0f : q[j];
          q[j] = base - te * ps[j];
        }
      }
#pragma unroll
      for (int j = 0; j < 16; ++j) invD[tid * 20 + j] = q[j];
    }
    __syncthreads();

    {
      const int r = tid & 127, h = tid >> 7;
      float mv[8];
      if ((r >> 4) == s) {
        const int rr = r & 15;
#pragma unroll
        for (int j = 0; j < 8; ++j) mv[j] = invD[rr * 20 + 8 * h + j];
      } else {
#pragma unroll
        for (int j = 0; j < 8; ++j) mv[j] = 0.f;
#pragma unroll
        for (int k = 0; k < 16; ++k) {
          const float pk = Pc[k * 132 + r];
          const float4 d0 = *(const float4*)&invD[k * 20 + 8 * h];
          const float4 d1 = *(const float4*)&invD[k * 20 + 8 * h + 4];
          mv[0] -= pk * d0.x; mv[1] -= pk * d0.y; mv[2] -= pk * d0.z; mv[3] -= pk * d0.w;
          mv[4] -= pk * d1.x; mv[5] -= pk * d1.y; mv[6] -= pk * d1.z; mv[7] -= pk * d1.w;
        }
      }
#pragma unroll
      for (int j = 0; j < 8; ++j) MBt[(8 * h + j) * 132 + r] = mv[j];
    }
    __syncthreads();

    if ((tj >> 1) == s) {
      const int c0 = (tj & 1) * 8;
#pragma unroll
      for (int j = 0; j < 8; ++j)
#pragma unroll
        for (int i = 0; i < 8; ++i) a[i][j] = MBt[(c0 + j) * 132 + R + i];
    } else {
      if ((ti >> 1) == s) {
#pragma unroll
        for (int i = 0; i < 8; ++i)
#pragma unroll
          for (int j = 0; j < 8; ++j) a[i][j] = 0.f;
      }
#pragma unroll
      for (int kk = 0; kk < 16; ++kk) {
        const float4 m0 = *(const float4*)&MBt[kk * 132 + R];
        const float4 m1 = *(const float4*)&MBt[kk * 132 + R + 4];
        const float4 p0 = *(const float4*)&Ar[kk * 132 + C];
        const float4 p1 = *(const float4*)&Ar[kk * 132 + C + 4];
        const float mi[8] = {m0.x, m0.y, m0.z, m0.w, m1.x, m1.y, m1.z, m1.w};
        const float pj[8] = {p0.x, p0.y, p0.z, p0.w, p1.x, p1.y, p1.z, p1.w};
#pragma unroll
        for (int i = 0; i < 8; ++i)
#pragma unroll
          for (int j = 0; j < 8; ++j) a[i][j] += mi[i] * pj[j];
      }
    }
    __syncthreads();
  }
#pragma unroll
  for (int i = 0; i < 8; ++i)
#pragma unroll
    for (int j = 0; j < 8; ++j) dstT[(C + j) * 128 + (R + i)] = a[i][j];
}

__device__ void dev_T(const float* __restrict__ u, float* __restrict__ vw, int bid,
                      int t, float* sm) {
  float* buf = sm;  // 64*65
  const int b0 = bid * 64;
#pragma unroll
  for (int h = 0; h < 2; ++h) {
#pragma unroll
    for (int q = 0; q < 16; ++q) {
      const int idx = q * 256 + t;
      const int bl = idx >> 6;
      const int i2 = idx & 63;
      buf[i2 * 65 + bl] = u[(b0 + bl) * 128 + 64 * h + i2];
    }
    __syncthreads();
#pragma unroll
    for (int q = 0; q < 16; ++q) {
      const int idx = q * 256 + t;
      const int i2 = idx >> 6;
      const int bl = idx & 63;
      vw[(256 + 64 * h + i2) * NB + b0 + bl] = buf[i2 * 65 + bl];
    }
    __syncthreads();
  }
}

__device__ void dev_du(const float* __restrict__ D12, const float* __restrict__ cx,
                       float* __restrict__ vw, int bid, int t, float* sm) {
  float* Dl = sm;  // 8*128
  const int bx = bid & 7;
  const int l0 = (bid >> 3) * 8;
#pragma unroll
  for (int q = 0; q < 4; ++q) Dl[q * 256 + t] = D12[l0 * 128 + q * 256 + t];
  __syncthreads();
  const float4* vw4 = (const float4*)vw;
  float4* vw4o = (float4*)vw;
  const int b4 = bx * 256 + t;
  float4 acc[8];
#pragma unroll
  for (int j = 0; j < 8; ++j) {
    const float cj = cx[l0 + j];
    acc[j] = make_float4(cj, cj, cj, cj);
  }
#pragma unroll 4
  for (int i = 0; i < 128; ++i) {
    const float4 wv = vw4[(256 + i) * 2048 + b4];
#pragma unroll
    for (int j = 0; j < 8; ++j) {
      const float d = Dl[j * 128 + i];
      acc[j].x += d * wv.x;
      acc[j].y += d * wv.y;
      acc[j].z += d * wv.z;
      acc[j].w += d * wv.w;
    }
  }
#pragma unroll
  for (int j = 0; j < 8; ++j) vw4o[(l0 + j) * 2048 + b4] = acc[j];
}

// W (TRANSPOSED: Wt[j][i] = W[i][j]) and z1  (A = E^T, c = C2^T)
__device__ void dev_WZ(const float* __restrict__ E, const float* __restrict__ C2,
                       const float* __restrict__ inv1T, float* __restrict__ Wt,
                       float* __restrict__ z1, int gid) {
  const int half = gid >> 14;
  const int idx = gid & 16383;
  const int j = idx >> 7;   // wave-uniform
  const int i = idx & 127;  // lane
  float s = 0.f;
  if (half == 0) {
    for (int m = 0; m < 128; ++m) s += inv1T[m * 128 + i] * E[(128 + j) * 256 + m];
    Wt[j * 128 + i] = s;  // coalesced store of W^T
  } else {
    for (int m = 0; m < 128; ++m) s += inv1T[m * 128 + i] * C2[j * 256 + m];
    z1[i * 128 + j] = s;
  }
}

// c2p = c2 - A21 z1
__device__ void dev_c2p(const float* __restrict__ E, const float* __restrict__ C2,
                        const float* __restrict__ z1, float* __restrict__ c2p,
                        int gid) {
  const int i = gid >> 7;   // wave-uniform
  const int o = gid & 127;  // lane
  float s = C2[o * 256 + 128 + i];
  for (int m = 0; m < 128; ++m) s -= E[m * 256 + 128 + i] * z1[m * 128 + o];
  c2p[i * 128 + o] = s;
}

// S^T = (A22 - A21 W)^T built by ONE block, then inv(S) by the same block
__device__ void dev_Sinv(const float* __restrict__ E, const float* __restrict__ Wt,
                         float* __restrict__ STt, float* __restrict__ inv2T, int t,
                         float* sm) {
  for (int q = 0; q < 64; ++q) {
    const int idx = q * 256 + t;
    const int jj = idx >> 7;  // wave-uniform
    const int i = idx & 127;  // lane
    float s = E[(128 + jj) * 256 + 128 + i];
    for (int m = 0; m < 128; ++m) s -= E[m * 256 + 128 + i] * Wt[jj * 128 + m];
    STt[jj * 128 + i] = s;
  }
  __threadfence_block();
  __syncthreads();
  dev_inv(STt, 128, inv2T, t, sm);
}

// merged G2+G1: block bo owns o-columns {2bo, 2bo+1}; g2 stashed in LDS for g1
__device__ void dev_G21(const float* __restrict__ inv2T, const float* __restrict__ c2p,
                        const float* __restrict__ Wt, const float* __restrict__ z1,
                        float* __restrict__ g2, float* __restrict__ g1, int bo, int t,
                        float* g2loc /* [2][128] */) {
  const int i = t & 127;   // lane
  const int oh = t >> 7;   // 0/1
  const int o = 2 * bo + oh;
  float s = 0.f;
  for (int m = 0; m < 128; ++m) s += inv2T[m * 128 + i] * c2p[m * 128 + o];
  g2loc[oh * 128 + i] = s;
  g2[i * 128 + o] = s;
  __syncthreads();
  float s1 = z1[i * 128 + o];
  for (int m = 0; m < 128; ++m) s1 -= Wt[m * 128 + i] * g2loc[oh * 128 + m];
  g1[i * 128 + o] = s1;
}

__device__ void dev_R(const float* __restrict__ B1, const float* __restrict__ B2,
                      const float* __restrict__ D21, const float* __restrict__ D22,
                      const float* __restrict__ g1, const float* __restrict__ g2,
                      const float* __restrict__ xF, float* __restrict__ R,
                      float* __restrict__ y0, int gid) {
  if (gid < 32768) {
    const int o = gid >> 8;
    const int l = gid & 255;
    float s = D21[o * 256 + l];
    for (int m = 0; m < 128; ++m) {
      s += g1[m * 128 + o] * B1[m * 256 + l];
      s += g2[m * 128 + o] * B1[(128 + m) * 256 + l];
    }
    R[o * 384 + l] = s;
  } else if (gid < 49152) {
    const int t2 = gid - 32768;
    const int o = t2 >> 7;
    const int i = t2 & 127;
    float s = D22[o * 128 + i];
    for (int m = 0; m < 128; ++m) {
      s += g1[m * 128 + o] * B2[m * 128 + i];
      s += g2[m * 128 + o] * B2[(128 + m) * 128 + i];
    }
    R[o * 384 + 256 + i] = s;
  } else if (gid < 49280) {
    const int o = gid - 49152;
    float s = 0.f;
    for (int m = 0; m < 128; ++m) {
      s += g1[m * 128 + o] * xF[m];
      s += g2[m * 128 + o] * xF[128 + m];
    }
    y0[o] = s;
  }
}

// ---------- FULL scan: eager right-looking, 64 columns/block, one live reg array --
// vfut[256][64] LDS holds v-inits (+accumulated cross-chunk updates). Per chunk:
// copy chunk rows to v[64] regs; verified cpack scan writes w back INTO v[] (register
// reuse -> ~85 live VGPRs, no spill); then push rank-64 contribution to all future
// rows: D11 row-segments via wave-uniform float4 loads (s_load), 64 FMA vs v[],
// one LDS RMW per future row. Single wave per block -> no barriers.
__device__ void dev_scanall(const float* __restrict__ cpack,
                            const float* __restrict__ rLam,
                            const float* __restrict__ D11, float* __restrict__ vw,
                            int bid, int t, float* vfut /* 256*64 floats */) {
  const int b = bid * 64 + t;
  // init: all 256 v-init rows, coalesced 64-wide, no dependencies
#pragma unroll 8
  for (int l = 0; l < 256; ++l) vfut[l * 64 + t] = vw[l * NB + b];

  for (int c = 0; c < 4; ++c) {  // NOT unrolled: one scan-body instance (icache)
    const int l0 = c * 64;
    float v[64];
    sfor<64>([&](auto LI) {
      constexpr int li = decltype(LI)::value;
      v[li] = vfut[(l0 + li) * 64 + t];
    });
    // in-chunk right-looking register scan (verified R5-R10 body), w -> v[li]
    const float4* cp4 = (const float4*)(cpack + c * CPACK_STRIDE);
    sfor<64>([&](auto LI) {
      constexpr int li = decltype(LI)::value;
      const float w = fast_tanh(v[li] * rLam[l0 + li]);
      v[li] = w;
      vw[(l0 + li) * NB + b] = w;
      constexpr int n = 63 - li;
      constexpr int off4 = coff(li) / 4;
      sfor<(n + 3) / 4>([&](auto Q) {
        constexpr int q = decltype(Q)::value;
        const float4 d = cp4[off4 + q];
        if constexpr (4 * q + 0 < n) v[li + 1 + 4 * q + 0] += d.x * w;
        if constexpr (4 * q + 1 < n) v[li + 1 + 4 * q + 1] += d.y * w;
        if constexpr (4 * q + 2 < n) v[li + 1 + 4 * q + 2] += d.z * w;
        if constexpr (4 * q + 3 < n) v[li + 1 + 4 * q + 3] += d.w * w;
      });
    });
    // eager cross-chunk update of all future rows
    for (int l2 = l0 + 64; l2 < 256; ++l2) {
      const float4* drow4 = (const float4*)(D11 + l2 * 256 + l0);  // wave-uniform
      float s0 = 0.f, s1 = 0.f, s2 = 0.f, s3 = 0.f;
#pragma unroll
      for (int q = 0; q < 16; ++q) {
        const float4 d = drow4[q];
        s0 += d.x * v[4 * q + 0];
        s1 += d.y * v[4 * q + 1];
        s2 += d.z * v[4 * q + 2];
        s3 += d.w * v[4 * q + 3];
      }
      vfut[l2 * 64 + t] += (s0 + s1) + (s2 + s3);
    }
  }
}

__device__ void dev_ky(const float* __restrict__ vw, const float* __restrict__ R,
                       const float* __restrict__ y0, float* __restrict__ y, int bid,
                       int tid, float* sm) {
  float* Rl = sm;  // 1536
  const int gx = bid & 7;   // b-tile (XCD-aligned)
  const int gy = bid >> 3;  // o-tile
  const int o0 = gy * 4;
#pragma unroll
  for (int q = 0; q < 6; ++q) Rl[q * 256 + tid] = R[o0 * 384 + q * 256 + tid];
  __syncthreads();
  const float4* vw4 = (const float4*)vw;
  const int b4 = gx * 256 + tid;
  float acc[4][4];
#pragma unroll
  for (int j = 0; j < 4; ++j) {
    const float y0j = y0[o0 + j];
#pragma unroll
    for (int bi = 0; bi < 4; ++bi) acc[bi][j] = y0j;
  }
#pragma unroll 4
  for (int k = 0; k < 384; k += 4) {
    const float4 w0 = vw4[(k + 0) * 2048 + b4];
    const float4 w1 = vw4[(k + 1) * 2048 + b4];
    const float4 w2 = vw4[(k + 2) * 2048 + b4];
    const float4 w3 = vw4[(k + 3) * 2048 + b4];
#pragma unroll
    for (int j = 0; j < 4; ++j) {
      const float4 r = *(const float4*)&Rl[j * 384 + k];
      acc[0][j] += r.x * w0.x + r.y * w1.x + r.z * w2.x + r.w * w3.x;
      acc[1][j] += r.x * w0.y + r.y * w1.y + r.z * w2.y + r.w * w3.y;
      acc[2][j] += r.x * w0.z + r.y * w1.z + r.z * w2.z + r.w * w3.z;
      acc[3][j] += r.x * w0.w + r.y * w1.w + r.z * w2.w + r.w * w3.w;
    }
  }
  const int b0 = b4 * 4;
#pragma unroll
  for (int bi = 0; bi < 4; ++bi) {
    *(float4*)&y[(b0 + bi) * 128 + o0] =
        make_float4(acc[bi][0], acc[bi][1], acc[bi][2], acc[bi][3]);
  }
}

// =================== mega kernels (6 launches, 5 junctions) ===================

__global__ __launch_bounds__(256) void mega1(const float* u, const float* x,
                                             const float* C1, const float* Fm,
                                             const float* Lam, const float* D11,
                                             const float* E, float* vw, float* cx,
                                             float* xF, float* rLam, float* cpack,
                                             float* inv1T) {
  __shared__ __align__(16) float sm[6656];
  const int bid = blockIdx.x;
  const int t = threadIdx.x;
  if (bid < 128) dev_T(u, vw, bid, t, sm);
  else if (bid == 128) dev_prep(x, C1, Fm, Lam, cx, xF, rLam, t);
  else if (bid == 129) dev_pack(D11, cpack, t);
  else dev_inv(E, 256, inv1T, t, sm);  // bid == 130
}

__global__ __launch_bounds__(256) void mega2(const float* D12, const float* cx,
                                             float* vw, const float* E,
                                             const float* C2, const float* inv1T,
                                             float* Wt, float* z1) {
  __shared__ __align__(16) float sm[1024];
  const int bid = blockIdx.x;
  const int t = threadIdx.x;
  if (bid < 256) dev_du(D12, cx, vw, bid, t, sm);
  else dev_WZ(E, C2, inv1T, Wt, z1, (bid - 256) * 256 + t);
}

__global__ __launch_bounds__(256) void mega3(const float* cpack, const float* rLam,
                                             const float* D11, float* vw,
                                             const float* E, const float* C2,
                                             const float* Wt, const float* z1,
                                             float* c2p, float* STt, float* inv2T) {
  __shared__ __align__(16) float smu[16384];  // union: vfut 64 KB / Sinv 26 KB
  const int bid = blockIdx.x;
  const int t = threadIdx.x;
  if (bid < 128) {
    if (t < 64) dev_scanall(cpack, rLam, D11, vw, bid, t, smu);
  } else if (bid < 192) {
    dev_c2p(E, C2, z1, c2p, (bid - 128) * 256 + t);
  } else {
    dev_Sinv(E, Wt, STt, inv2T, t, smu);  // bid == 192
  }
}

__global__ __launch_bounds__(256) void mega4(const float* inv2T, const float* c2p,
                                             const float* Wt, const float* z1,
                                             float* g2, float* g1) {
  __shared__ float g2loc[2 * 128];
  dev_G21(inv2T, c2p, Wt, z1, g2, g1, blockIdx.x, threadIdx.x, g2loc);
}

__global__ __launch_bounds__(256) void mega5(const float* B1, const float* B2,
                                             const float* D21, const float* D22,
                                             const float* g1, const float* g2,
                                             const float* xF, float* R, float* y0) {
  dev_R(B1, B2, D21, D22, g1, g2, xF, R, y0, blockIdx.x * 256 + threadIdx.x);
}

__global__ __launch_bounds__(256) void mega6(const float* vw, const float* R,
                                             const float* y0, float* y) {
  __shared__ __align__(16) float sm[1536];
  dev_ky(vw, R, y0, y, blockIdx.x, threadIdx.x, sm);
}

extern "C" void kernel_launch(void* const* d_in, const int* in_sizes, int n_in,
                              void* d_out, int out_size, void* d_ws, size_t ws_size,
                              hipStream_t stream) {
  const float* u   = (const float*)d_in[0];
  const float* x   = (const float*)d_in[1];
  const float* Fm  = (const float*)d_in[2];
  const float* B1  = (const float*)d_in[3];
  const float* B2  = (const float*)d_in[4];
  const float* C1  = (const float*)d_in[5];
  const float* C2  = (const float*)d_in[6];
  const float* D11 = (const float*)d_in[7];
  const float* D12 = (const float*)d_in[8];
  const float* D21 = (const float*)d_in[9];
  const float* D22 = (const float*)d_in[10];
  const float* E   = (const float*)d_in[11];
  const float* Lam = (const float*)d_in[12];
  float* y = (float*)d_out;

  float* F = (float*)d_ws;  // ~13.4 MB used
  float* vw    = F;         // 384*8192 (rows 256..383 = u^T)
  float* SMb   = F + 384 * NB;
  float* inv1T = SMb;            // 16384
  float* Wt    = SMb + 16384;    // W transposed
  float* z1    = SMb + 32768;
  float* STt   = SMb + 49152;
  float* c2p   = SMb + 65536;
  float* inv2T = SMb + 81920;
  float* g2    = SMb + 98304;
  float* g1    = SMb + 114688;
  float* Rm    = SMb + 131072;   // 128*384
  float* y0v   = SMb + 180224;   // 128
  float* cx    = SMb + 180352;   // 256
  float* xF    = SMb + 180608;   // 256
  float* rLam  = SMb + 180864;   // 256
  float* cpack = SMb + 181120;   // 4*2176

  mega1<<<131, 256, 0, stream>>>(u, x, C1, Fm, Lam, D11, E, vw, cx, xF, rLam,
                                 cpack, inv1T);
  mega2<<<384, 256, 0, stream>>>(D12, cx, vw, E, C2, inv1T, Wt, z1);
  mega3<<<193, 256, 0, stream>>>(cpack, rLam, D11, vw, E, C2, Wt, z1, c2p, STt,
                                 inv2T);
  mega4<<<64, 256, 0, stream>>>(inv2T, c2p, Wt, z1, g2, g1);
  mega5<<<193, 256, 0, stream>>>(B1, B2, D21, D22, g1, g2, xF, Rm, y0v);
  mega6<<<256, 256, 0, stream>>>(vw, Rm, y0v, y);
}